// Round 11
// baseline (257.362 us; speedup 1.0000x reference)
//
#include <hip/hip_runtime.h>
#include <hip/hip_bf16.h>
#include <math.h>

// GCN 2-layer: out = log_softmax( GCN2( relu( GCN1(x) ) ) )
// GCNConv: out = D^-1/2 A D^-1/2 (X W) + (X W)/deg + b,  deg = 1 + indeg(dst)
//
// Round 27 (from r26=228.9 best; gemm1_bin pinned at ~53us across r21/r22/r26
// while gemm compute changed radically -> the BIN half is the critical path):
//  - bin parallelism 512 -> 1280 blocks (seg=1250, ~5/CU); each thread holds
//    its 5 edges in REGISTERS across passes (kills the pass-2 re-read of
//    src/dst, -6.4MB FETCH). srec 5KB.
//  - W1t staging XOR-swizzled (k ^= (c&7)<<4, same map on write+read):
//    8-way bank conflict -> 2-way (free). Verified: 16 lanes tile 32 banks.
//  - gemm1/gemm2 MFMA forms, scatter_csr, agg1, agg2: unchanged from r26.

#define CAP 48
#define NBSHIFT 8
#define SCNODES 256            // 1 << NBSHIFT
#define BCAP 6144              // expected 4096 edges/bucket, + headroom
#define EPT 5                  // edges per thread in bin (seg <= 1280)
typedef unsigned short u16;
typedef __attribute__((ext_vector_type(8))) short bf16x8;
typedef __attribute__((ext_vector_type(4))) float f32x4;

__device__ __forceinline__ u16 f2bf(float f) {
    __hip_bfloat16 h = __float2bfloat16(f);
    return *reinterpret_cast<u16*>(&h);
}
__device__ __forceinline__ float bf2f(u16 u) {
    return __uint_as_float(((unsigned)u) << 16);
}

// ---------------- fused: bin (blocks [0,BINB)) || gemm1 (blocks [BINB,BINB+GB)) ---------------
// gemm1 LDS: W1t bf16 [64][136] = 17408 B. bin LDS: 6144 + srec 5120 = 11264 B.

#define FUSED_SMEM 17408

__global__ __launch_bounds__(256) void gemm1_bin(const float* __restrict__ X,
                                                 const float* __restrict__ W,
                                                 u16* __restrict__ OUT,
                                                 const int* __restrict__ src,
                                                 const int* __restrict__ dst,
                                                 int* __restrict__ gtail,
                                                 int* __restrict__ bucketed,
                                                 int N, int E, int NB, int seg, int BINB) {
    __shared__ __align__(16) char smem[FUSED_SMEM];
    const int t = threadIdx.x;

    if ((int)blockIdx.x >= BINB) {
        // ---- gemm1: OUT[N,64] = X[N,128] @ W1[128,64], bf16 out; MFMA ----
        u16* W1t = (u16*)smem;                 // [64 cols][136 k] bf16, k XOR-swizzled
        const int row0 = ((int)blockIdx.x - BINB) * 64;
        // stage W1 transposed+swizzled -> bf16 (once)
        for (int i = t; i < 128 * 64; i += 256) {
            int k = i >> 6, c = i & 63;
            W1t[c * 136 + (k ^ ((c & 7) << 4))] = f2bf(W[i]);
        }
        __syncthreads();

        const int wave = t >> 6;
        const int lane = t & 63;
        const int rA = lane & 15;              // A-row / B-col / D-col within tile
        const int g  = lane >> 4;              // lane group (k-slot / D-row group)
        const int m  = row0 + wave * 16 + rA;
        f32x4 acc[4] = {{0.f,0.f,0.f,0.f},{0.f,0.f,0.f,0.f},
                        {0.f,0.f,0.f,0.f},{0.f,0.f,0.f,0.f}};

        #pragma unroll
        for (int s = 0; s < 4; s++) {
            bf16x8 ahi = {0,0,0,0,0,0,0,0}, alo = {0,0,0,0,0,0,0,0};
            if (m < N) {
                const float* xp = X + (size_t)m * 128 + s * 32 + g * 8;
                float4 v0 = *reinterpret_cast<const float4*>(xp);
                float4 v1 = *reinterpret_cast<const float4*>(xp + 4);
                float xv[8] = {v0.x, v0.y, v0.z, v0.w, v1.x, v1.y, v1.z, v1.w};
                #pragma unroll
                for (int i = 0; i < 8; i++) {
                    u16 hb = f2bf(xv[i]);
                    ahi[i] = (short)hb;
                    alo[i] = (short)f2bf(xv[i] - bf2f(hb));
                }
            }
            #pragma unroll
            for (int ct = 0; ct < 4; ct++) {
                int col = ct * 16 + rA;
                int koff = (s * 32 + g * 8) ^ ((col & 7) << 4);
                bf16x8 bfr = *reinterpret_cast<const bf16x8*>(&W1t[col * 136 + koff]);
                acc[ct] = __builtin_amdgcn_mfma_f32_16x16x32_bf16(ahi, bfr, acc[ct], 0, 0, 0);
                acc[ct] = __builtin_amdgcn_mfma_f32_16x16x32_bf16(alo, bfr, acc[ct], 0, 0, 0);
            }
        }
        #pragma unroll
        for (int ct = 0; ct < 4; ct++)
            #pragma unroll
            for (int j = 0; j < 4; j++) {
                int mr = row0 + wave * 16 + g * 4 + j;
                if (mr < N) OUT[(size_t)mr * 64 + ct * 16 + rA] = f2bf(acc[ct][j]);
            }
    } else {
        // ---- bin: edges held in registers; LDS bucket sort -> contiguous run writes ----
        int* hist  = (int*)smem;              // [512]
        int* scan  = hist + 512;              // [512] -> exclusive prefix (lbase)
        int* gbase = scan + 512;              // [512]
        int* srec  = (int*)(smem + 6144);     // [1280]
        const int bid = blockIdx.x;

        const int b0 = bid * seg;
        const int b1 = min(b0 + seg, E);
        const int n = b1 - b0;

        int2 ed[EPT];
        #pragma unroll
        for (int i = 0; i < EPT; i++) {
            int e = b0 + t + i * 256;
            bool ok = e < b1;
            ed[i].x = ok ? src[e] : 0;
            ed[i].y = ok ? dst[e] : -1;
        }

        hist[t] = 0; hist[t + 256] = 0;
        __syncthreads();
        #pragma unroll
        for (int i = 0; i < EPT; i++)
            if (ed[i].y >= 0) atomicAdd(&hist[ed[i].y >> NBSHIFT], 1);
        __syncthreads();
        int c0 = hist[t], c1 = hist[t + 256];
        gbase[t]       = c0 ? atomicAdd(&gtail[t], c0) : 0;
        gbase[t + 256] = c1 ? atomicAdd(&gtail[t + 256], c1) : 0;
        scan[t] = c0; scan[t + 256] = c1;
        hist[t] = 0; hist[t + 256] = 0;     // running offsets for pass2
        __syncthreads();
        #pragma unroll
        for (int d = 1; d < 512; d <<= 1) {
            int v0 = (t >= d) ? scan[t - d] : 0;
            int v1 = scan[t + 256 - d];
            __syncthreads();
            scan[t] += v0; scan[t + 256] += v1;
            __syncthreads();
        }
        scan[t] -= c0; scan[t + 256] -= c1;
        __syncthreads();
        // pass2: scatter packed records from registers into LDS-sorted buffer
        #pragma unroll
        for (int i = 0; i < EPT; i++)
            if (ed[i].y >= 0) {
                int d = ed[i].y;
                int b = d >> NBSHIFT;
                int off = atomicAdd(&hist[b], 1);
                srec[scan[b] + off] = (ed[i].x << NBSHIFT) | (d & (SCNODES - 1));
            }
        __syncthreads();
        // pass3: per-bucket run emit; consecutive records -> consecutive global addrs
        for (int b = t; b < NB; b += 256) {
            int lb = scan[b];
            int le = (b + 1 < 512) ? scan[b + 1] : n;
            int gb = gbase[b];
            for (int i = lb; i < le; i++) {
                int gpos = gb + (i - lb);
                if (gpos < BCAP) bucketed[(size_t)b * BCAP + gpos] = srec[i];
            }
        }
    }
}

// ---------------- scatter: LDS slot assignment within a 256-node bucket ----------------

__global__ __launch_bounds__(512) void scatter_csr(const int* __restrict__ bucketed,
                                                   const int* __restrict__ gtail,
                                                   int* __restrict__ cnt,
                                                   int* __restrict__ csr_src,
                                                   float* __restrict__ dinv, int N) {
    __shared__ int cntL[SCNODES];
    __shared__ __align__(16) int csrL[SCNODES * CAP];   // 48 KB
    const int b = blockIdx.x;
    const int t = threadIdx.x;
    for (int i = t; i < SCNODES; i += 512) cntL[i] = 0;
    __syncthreads();

    int n = gtail[b]; if (n > BCAP) n = BCAP;
    const int* p = bucketed + (size_t)b * BCAP;
    for (int i = t; i < n; i += 512) {
        int rec = p[i];
        int l = rec & (SCNODES - 1);
        int slot = atomicAdd(&cntL[l], 1);
        if (slot < CAP) csrL[l * CAP + slot] = rec >> NBSHIFT;
    }
    __syncthreads();

    const int v0 = b << NBSHIFT;
    const int lim = min(SCNODES, N - v0);
    if (lim <= 0) return;
    int4* dst4 = reinterpret_cast<int4*>(&csr_src[(size_t)v0 * CAP]);
    const int4* src4 = reinterpret_cast<const int4*>(csrL);
    for (int i = t; i < lim * (CAP / 4); i += 512) dst4[i] = src4[i];
    for (int i = t; i < lim; i += 512) {
        int cv = cntL[i];
        cnt[v0 + i] = cv;
        dinv[v0 + i] = rsqrtf((float)cv + 1.0f);
    }
}

// ---------------- gemm2: hw2[N,64] = h[N,64](bf16) @ W2[64,47] (zero-padded), MFMA ------------

__global__ __launch_bounds__(256) void gemm2_mfma(const u16* __restrict__ X,
                                                  const float* __restrict__ W,
                                                  u16* __restrict__ OUT, int N) {
    __shared__ __align__(16) u16 W2t[64 * 72];   // [64 cols][72 k] bf16, 9216 B
    const int t = threadIdx.x;
    for (int i = t; i < 64 * 64; i += 256) {
        int k = i >> 6, c = i & 63;
        W2t[c * 72 + k] = (c < 47) ? f2bf(W[k * 47 + c]) : (u16)0;
    }
    __syncthreads();

    const int wave = t >> 6;
    const int lane = t & 63;
    const int rA = lane & 15;
    const int g  = lane >> 4;
    const int row0 = blockIdx.x * 64;
    const int m = row0 + wave * 16 + rA;
    f32x4 acc[4] = {{0.f,0.f,0.f,0.f},{0.f,0.f,0.f,0.f},
                    {0.f,0.f,0.f,0.f},{0.f,0.f,0.f,0.f}};

    #pragma unroll
    for (int s = 0; s < 2; s++) {
        bf16x8 a = {0,0,0,0,0,0,0,0};
        if (m < N) a = *reinterpret_cast<const bf16x8*>(&X[(size_t)m * 64 + s * 32 + g * 8]);
        #pragma unroll
        for (int ct = 0; ct < 4; ct++) {
            bf16x8 bfr = *reinterpret_cast<const bf16x8*>(
                &W2t[(ct * 16 + rA) * 72 + s * 32 + g * 8]);
            acc[ct] = __builtin_amdgcn_mfma_f32_16x16x32_bf16(a, bfr, acc[ct], 0, 0, 0);
        }
    }
    #pragma unroll
    for (int ct = 0; ct < 4; ct++)
        #pragma unroll
        for (int j = 0; j < 4; j++) {
            int mr = row0 + wave * 16 + g * 4 + j;
            if (mr < N) OUT[(size_t)mr * 64 + ct * 16 + rA] = f2bf(acc[ct][j]);
        }
}

// 8 bf16 (uint4) * w accumulated into acc[8]
__device__ __forceinline__ void fma_bf8(uint4 q, float w, float* acc) {
    acc[0] = fmaf(__uint_as_float(q.x << 16),          w, acc[0]);
    acc[1] = fmaf(__uint_as_float(q.x & 0xffff0000u),  w, acc[1]);
    acc[2] = fmaf(__uint_as_float(q.y << 16),          w, acc[2]);
    acc[3] = fmaf(__uint_as_float(q.y & 0xffff0000u),  w, acc[3]);
    acc[4] = fmaf(__uint_as_float(q.z << 16),          w, acc[4]);
    acc[5] = fmaf(__uint_as_float(q.z & 0xffff0000u),  w, acc[5]);
    acc[6] = fmaf(__uint_as_float(q.w << 16),          w, acc[6]);
    acc[7] = fmaf(__uint_as_float(q.w & 0xffff0000u),  w, acc[7]);
}

// Gather-accumulate over one 32-slot block. Row gathers are inline-asm volatile
// global_load_dwordx4 (un-collapsible -> all stay in flight until one vmcnt).
#define AGG_BLOCK(TBL, SRCV, SHIFT, UMAX)                                             \
    {                                                                                 \
        int s8[UMAX];                                                                 \
        _Pragma("unroll")                                                             \
        for (int u = 0; u < UMAX; u++)                                                \
            s8[u] = __shfl(SRCV, base + u * 4 + r);                                   \
        float d8[UMAX]; uint4 q8[UMAX];                                               \
        _Pragma("unroll")                                                             \
        for (int u = 0; u < UMAX; u++) {                                              \
            if ((SHIFT) + u * 4 < cemax) {                                            \
                d8[u] = dinv[s8[u]];                                                  \
                const u16* ap = &TBL[(size_t)s8[u] * 64 + b * 8];                     \
                asm volatile("global_load_dwordx4 %0, %1, off"                        \
                             : "=v"(q8[u]) : "v"(ap));                                \
            }                                                                         \
        }                                                                             \
        asm volatile("s_waitcnt vmcnt(0)" ::: "memory");                              \
        __builtin_amdgcn_sched_barrier(0);                                            \
        _Pragma("unroll")                                                             \
        for (int u = 0; u < UMAX; u++) {                                              \
            if ((SHIFT) + u * 4 < cemax) {                                            \
                int e = (SHIFT) + u * 4 + r;                                          \
                float w = (e <= c) ? d8[u] * dv : 0.f;                                \
                fma_bf8(q8[u], w, acc);                                               \
            }                                                                         \
        }                                                                             \
    }

// ---------------- layer-1 aggregation: h = relu(agg + xw/deg + b1), F=64, bf16 out -------------

__global__ __launch_bounds__(256, 4) void agg1_relu(const u16* __restrict__ xw,
                                                    const int* __restrict__ csr_src,
                                                    const int* __restrict__ cnt,
                                                    const float* __restrict__ dinv,
                                                    const float* __restrict__ bias,
                                                    u16* __restrict__ h, int N) {
    const int wid = (blockIdx.x * 256 + threadIdx.x) >> 6;
    const int lane = threadIdx.x & 63;
    const int v = wid * 2 + (lane >> 5);
    if (wid * 2 >= N) return;
    const bool okv = v < N;
    const int vs = okv ? v : 0;
    const int hl = lane & 31;
    int c = okv ? cnt[vs] : 0; if (c > CAP - 1) c = CAP - 1;
    const float dv = okv ? dinv[vs] : 0.f;
    int rawA = csr_src[vs * CAP + hl];
    int sA = (hl < c) ? rawA : ((hl == c) ? vs : 0);

    int ce = c + 1;
    int cemax = max(ce, __shfl_xor(ce, 32));
    const int r = hl >> 3, b = hl & 7;
    const int base = lane & 32;
    float acc[8] = {};

    AGG_BLOCK(xw, sA, 0, 8)
    if (cemax > 32) {   // rare (deg >= 32): slots 32..47
        int rawB = csr_src[vs * CAP + 32 + hl];   // hl>=16 reads pad, never selected
        int hl32 = hl + 32;
        int sB = (hl32 < c) ? rawB : ((hl32 == c) ? vs : 0);
        AGG_BLOCK(xw, sB, 32, 4)
    }

    #pragma unroll
    for (int u = 0; u < 8; u++) {
        acc[u] += __shfl_xor(acc[u], 8);
        acc[u] += __shfl_xor(acc[u], 16);
    }
    if (r == 0 && okv) {
        ushort4 oA, oB;
        oA.x = f2bf(fmaxf(acc[0] + bias[b * 8 + 0], 0.f));
        oA.y = f2bf(fmaxf(acc[1] + bias[b * 8 + 1], 0.f));
        oA.z = f2bf(fmaxf(acc[2] + bias[b * 8 + 2], 0.f));
        oA.w = f2bf(fmaxf(acc[3] + bias[b * 8 + 3], 0.f));
        oB.x = f2bf(fmaxf(acc[4] + bias[b * 8 + 4], 0.f));
        oB.y = f2bf(fmaxf(acc[5] + bias[b * 8 + 5], 0.f));
        oB.z = f2bf(fmaxf(acc[6] + bias[b * 8 + 6], 0.f));
        oB.w = f2bf(fmaxf(acc[7] + bias[b * 8 + 7], 0.f));
        u16* dstp = &h[(size_t)v * 64 + b * 8];
        *reinterpret_cast<ushort4*>(dstp)     = oA;
        *reinterpret_cast<ushort4*>(dstp + 4) = oB;
    }
}

// ---------------- layer-2 aggregation fused with log_softmax, F=47 (rows padded to 64) ----------

__global__ __launch_bounds__(256, 4) void agg2_lsm(const u16* __restrict__ hw,
                                                   const int* __restrict__ csr_src,
                                                   const int* __restrict__ cnt,
                                                   const float* __restrict__ dinv,
                                                   const float* __restrict__ bias,
                                                   float* __restrict__ out, int N) {
    const int wid = (blockIdx.x * 256 + threadIdx.x) >> 6;
    const int lane = threadIdx.x & 63;
    const int v = wid * 2 + (lane >> 5);
    if (wid * 2 >= N) return;
    const bool okv = v < N;
    const int vs = okv ? v : 0;
    const int hl = lane & 31;
    int c = okv ? cnt[vs] : 0; if (c > CAP - 1) c = CAP - 1;
    const float dv = okv ? dinv[vs] : 0.f;
    int rawA = csr_src[vs * CAP + hl];
    int sA = (hl < c) ? rawA : ((hl == c) ? vs : 0);

    int ce = c + 1;
    int cemax = max(ce, __shfl_xor(ce, 32));
    const int r = hl >> 3, b = hl & 7;
    const int base = lane & 32;
    float acc[8] = {};

    AGG_BLOCK(hw, sA, 0, 8)
    if (cemax > 32) {
        int rawB = csr_src[vs * CAP + 32 + hl];
        int hl32 = hl + 32;
        int sB = (hl32 < c) ? rawB : ((hl32 == c) ? vs : 0);
        AGG_BLOCK(hw, sB, 32, 4)
    }

    #pragma unroll
    for (int u = 0; u < 8; u++) {
        acc[u] += __shfl_xor(acc[u], 8);
        acc[u] += __shfl_xor(acc[u], 16);
    }
    const int f0 = b * 8;
    float val[8];
    #pragma unroll
    for (int u = 0; u < 8; u++) {
        int f = f0 + u;
        val[u] = (f < 47) ? acc[u] + bias[f] : -INFINITY;
    }
    float m = val[0];
    #pragma unroll
    for (int u = 1; u < 8; u++) m = fmaxf(m, val[u]);
    m = fmaxf(m, __shfl_xor(m, 1));
    m = fmaxf(m, __shfl_xor(m, 2));
    m = fmaxf(m, __shfl_xor(m, 4));
    float s = 0.f;
    #pragma unroll
    for (int u = 0; u < 8; u++)
        s += (f0 + u < 47) ? __expf(val[u] - m) : 0.f;
    s += __shfl_xor(s, 1);
    s += __shfl_xor(s, 2);
    s += __shfl_xor(s, 4);
    float ls = m + __logf(s);
    if (r == 0 && okv) {
        #pragma unroll
        for (int u = 0; u < 8; u++) {
            int f = f0 + u;
            if (f < 47) out[(size_t)v * 47 + f] = val[u] - ls;
        }
    }
}

// ---------------- launch ----------------

extern "C" void kernel_launch(void* const* d_in, const int* in_sizes, int n_in,
                              void* d_out, int out_size, void* d_ws, size_t ws_size,
                              hipStream_t stream) {
    const float* x  = (const float*)d_in[0];
    const int*   ei = (const int*)d_in[1];
    const float* W1 = (const float*)d_in[2];
    const float* b1 = (const float*)d_in[3];
    const float* W2 = (const float*)d_in[4];
    const float* b2 = (const float*)d_in[5];
    float* out = (float*)d_out;

    const int N = in_sizes[0] / 128;
    const int E = in_sizes[1] / 2;
    const int* src = ei;
    const int* dst = ei + E;
    const int NB = ((N - 1) >> NBSHIFT) + 1;   // 391 for N=100000

    char* ws = (char*)d_ws;
    size_t off = 0;
    auto alloc = [&](size_t bytes) {
        void* p = ws + off;
        off += (bytes + 255) & ~(size_t)255;
        return p;
    };
    int*   cnt      = (int*)  alloc((size_t)N * 4);
    int*   gtail    = (int*)  alloc((size_t)512 * 4);
    float* dinv     = (float*)alloc((size_t)N * 4);
    int*   csr_src  = (int*)  alloc(((size_t)N * CAP + 64) * 4);   // +pad for rawB overread
    u16*   xw1      = (u16*)  alloc((size_t)N * 64 * 2);
    int*   bucketed = (int*)  alloc((size_t)NB * BCAP * 4);        // 9.6 MB packed
    u16*   hbuf     = (u16*)  alloc((size_t)N * 64 * 2);
    u16*   hw2      = (u16*)  alloc((size_t)N * 64 * 2);

    hipMemsetAsync(gtail, 0, 512 * 4, stream);

    const int GB = (N + 63) / 64;              // 1563 gemm blocks (64 rows each)
    const int BINB = 1280;
    const int seg = (E + BINB - 1) / BINB;     // 1250 <= EPT*256
    gemm1_bin<<<BINB + GB, 256, 0, stream>>>(x, W1, xw1, src, dst, gtail, bucketed,
                                             N, E, NB, seg, BINB);
    scatter_csr<<<NB, 512, 0, stream>>>(bucketed, gtail, cnt, csr_src, dinv, N);
    agg1_relu<<<(N + 7) / 8, 256, 0, stream>>>(xw1, csr_src, cnt, dinv, b1, hbuf, N);
    gemm2_mfma<<<(N + 63) / 64, 256, 0, stream>>>(hbuf, W2, hw2, N);
    agg2_lsm<<<(N + 7) / 8, 256, 0, stream>>>(hw2, csr_src, cnt, dinv, b2, out, N);
}

// Round 12
// 228.236 us; speedup vs baseline: 1.1276x; 1.1276x over previous
//
#include <hip/hip_runtime.h>
#include <hip/hip_bf16.h>
#include <math.h>

// GCN 2-layer: out = log_softmax( GCN2( relu( GCN1(x) ) ) )
// GCNConv: out = D^-1/2 A D^-1/2 (X W) + (X W)/deg + b,  deg = 1 + indeg(dst)
//
// Round 28 (from r26=228.9 best; r27's BINB=1280 + W1t swizzle both failed:
// WRITE +7MB from 3-edge bucket runs, conflicts unchanged 2.2M -> swizzle
// ineffective; bin at 512 blocks was NOT parallelism-limited):
//  - gemm1 MFMA + bin: exact r26 form (BINB=512, no swizzle), EXCEPT bin
//    edges held in registers (EPT=13 @ seg=3125) -> pass2's 12.8MB src/dst
//    re-read removed (one global pass over the edge list).
//  - scatter_csr: 512 -> 1024 threads/block (same 49KB LDS, same 391-block
//    grid -> half the per-block serial depth; it was est. 25-40us, grid-
//    limited at 1.5 blocks/CU, never touched since r19).
//  - gemm2 MFMA / agg1 / agg2: byte-identical to r26.

#define CAP 48
#define NBSHIFT 8
#define SCNODES 256            // 1 << NBSHIFT
#define BCAP 6144              // expected 4096 edges/bucket, + headroom
#define EPT 13                 // edges per thread in bin (seg=3125 <= 13*256)
typedef unsigned short u16;
typedef __attribute__((ext_vector_type(8))) short bf16x8;
typedef __attribute__((ext_vector_type(4))) float f32x4;

__device__ __forceinline__ u16 f2bf(float f) {
    __hip_bfloat16 h = __float2bfloat16(f);
    return *reinterpret_cast<u16*>(&h);
}
__device__ __forceinline__ float bf2f(u16 u) {
    return __uint_as_float(((unsigned)u) << 16);
}

// ---------------- fused: bin (blocks [0,512)) || gemm1 (blocks [512,512+GB)) ----------------
// bin LDS: hist/scan/gbase 6144 + srec 12800 = 18944 B.
// gemm1 LDS: W1t bf16 [64][136] = 17408 B.  FUSED_SMEM = 18944.

#define FUSED_SMEM 18944

__global__ __launch_bounds__(256) void gemm1_bin(const float* __restrict__ X,
                                                 const float* __restrict__ W,
                                                 u16* __restrict__ OUT,
                                                 const int* __restrict__ src,
                                                 const int* __restrict__ dst,
                                                 int* __restrict__ gtail,
                                                 int* __restrict__ bucketed,
                                                 int N, int E, int NB, int seg, int BINB) {
    __shared__ __align__(16) char smem[FUSED_SMEM];
    const int t = threadIdx.x;

    if ((int)blockIdx.x >= BINB) {
        // ---- gemm1: OUT[N,64] = X[N,128] @ W1[128,64], bf16 out; MFMA ----
        u16* W1t = (u16*)smem;                 // [64 cols][136 k] bf16
        const int row0 = ((int)blockIdx.x - BINB) * 64;
        // stage W1 transposed -> bf16 (once)
        for (int i = t; i < 128 * 64; i += 256) {
            int k = i >> 6, c = i & 63;
            W1t[c * 136 + k] = f2bf(W[i]);
        }
        __syncthreads();

        const int wave = t >> 6;
        const int lane = t & 63;
        const int rA = lane & 15;              // A-row / B-col / D-col within tile
        const int g  = lane >> 4;              // lane group (k-slot / D-row group)
        const int m  = row0 + wave * 16 + rA;
        f32x4 acc[4] = {{0.f,0.f,0.f,0.f},{0.f,0.f,0.f,0.f},
                        {0.f,0.f,0.f,0.f},{0.f,0.f,0.f,0.f}};

        #pragma unroll
        for (int s = 0; s < 4; s++) {
            bf16x8 ahi = {0,0,0,0,0,0,0,0}, alo = {0,0,0,0,0,0,0,0};
            if (m < N) {
                const float* xp = X + (size_t)m * 128 + s * 32 + g * 8;
                float4 v0 = *reinterpret_cast<const float4*>(xp);
                float4 v1 = *reinterpret_cast<const float4*>(xp + 4);
                float xv[8] = {v0.x, v0.y, v0.z, v0.w, v1.x, v1.y, v1.z, v1.w};
                #pragma unroll
                for (int i = 0; i < 8; i++) {
                    u16 hb = f2bf(xv[i]);
                    ahi[i] = (short)hb;
                    alo[i] = (short)f2bf(xv[i] - bf2f(hb));
                }
            }
            #pragma unroll
            for (int ct = 0; ct < 4; ct++) {
                bf16x8 bfr = *reinterpret_cast<const bf16x8*>(
                    &W1t[(ct * 16 + rA) * 136 + s * 32 + g * 8]);
                acc[ct] = __builtin_amdgcn_mfma_f32_16x16x32_bf16(ahi, bfr, acc[ct], 0, 0, 0);
                acc[ct] = __builtin_amdgcn_mfma_f32_16x16x32_bf16(alo, bfr, acc[ct], 0, 0, 0);
            }
        }
        #pragma unroll
        for (int ct = 0; ct < 4; ct++)
            #pragma unroll
            for (int j = 0; j < 4; j++) {
                int mr = row0 + wave * 16 + g * 4 + j;
                if (mr < N) OUT[(size_t)mr * 64 + ct * 16 + rA] = f2bf(acc[ct][j]);
            }
    } else {
        // ---- bin: edges in registers; LDS bucket sort -> contiguous run writes ----
        int* hist  = (int*)smem;              // [512]
        int* scan  = hist + 512;              // [512] -> exclusive prefix (lbase)
        int* gbase = scan + 512;              // [512]
        int* srec  = (int*)(smem + 6144);     // [3200]
        const int bid = blockIdx.x;

        const int b0 = bid * seg;
        const int b1 = min(b0 + seg, E);
        const int n = b1 - b0;

        int2 ed[EPT];
        #pragma unroll
        for (int i = 0; i < EPT; i++) {
            int e = b0 + t + i * 256;
            bool ok = e < b1;
            ed[i].x = ok ? src[e] : 0;
            ed[i].y = ok ? dst[e] : -1;
        }

        hist[t] = 0; hist[t + 256] = 0;
        __syncthreads();
        #pragma unroll
        for (int i = 0; i < EPT; i++)
            if (ed[i].y >= 0) atomicAdd(&hist[ed[i].y >> NBSHIFT], 1);
        __syncthreads();
        int c0 = hist[t], c1 = hist[t + 256];
        gbase[t]       = c0 ? atomicAdd(&gtail[t], c0) : 0;
        gbase[t + 256] = c1 ? atomicAdd(&gtail[t + 256], c1) : 0;
        scan[t] = c0; scan[t + 256] = c1;
        hist[t] = 0; hist[t + 256] = 0;     // running offsets for pass2
        __syncthreads();
        #pragma unroll
        for (int d = 1; d < 512; d <<= 1) {
            int v0 = (t >= d) ? scan[t - d] : 0;
            int v1 = scan[t + 256 - d];
            __syncthreads();
            scan[t] += v0; scan[t + 256] += v1;
            __syncthreads();
        }
        scan[t] -= c0; scan[t + 256] -= c1;
        __syncthreads();
        // pass2: scatter packed records from registers into LDS-sorted buffer
        #pragma unroll
        for (int i = 0; i < EPT; i++)
            if (ed[i].y >= 0) {
                int d = ed[i].y;
                int b = d >> NBSHIFT;
                int off = atomicAdd(&hist[b], 1);
                srec[scan[b] + off] = (ed[i].x << NBSHIFT) | (d & (SCNODES - 1));
            }
        __syncthreads();
        // pass3: per-bucket run emit; consecutive records -> consecutive global addrs
        for (int b = t; b < NB; b += 256) {
            int lb = scan[b];
            int le = (b + 1 < 512) ? scan[b + 1] : n;
            int gb = gbase[b];
            for (int i = lb; i < le; i++) {
                int gpos = gb + (i - lb);
                if (gpos < BCAP) bucketed[(size_t)b * BCAP + gpos] = srec[i];
            }
        }
    }
}

// ---------------- scatter: LDS slot assignment within a 256-node bucket ----------------

__global__ __launch_bounds__(1024) void scatter_csr(const int* __restrict__ bucketed,
                                                    const int* __restrict__ gtail,
                                                    int* __restrict__ cnt,
                                                    int* __restrict__ csr_src,
                                                    float* __restrict__ dinv, int N) {
    __shared__ int cntL[SCNODES];
    __shared__ __align__(16) int csrL[SCNODES * CAP];   // 48 KB
    const int b = blockIdx.x;
    const int t = threadIdx.x;
    for (int i = t; i < SCNODES; i += 1024) cntL[i] = 0;
    __syncthreads();

    int n = gtail[b]; if (n > BCAP) n = BCAP;
    const int* p = bucketed + (size_t)b * BCAP;
    for (int i = t; i < n; i += 1024) {
        int rec = p[i];
        int l = rec & (SCNODES - 1);
        int slot = atomicAdd(&cntL[l], 1);
        if (slot < CAP) csrL[l * CAP + slot] = rec >> NBSHIFT;
    }
    __syncthreads();

    const int v0 = b << NBSHIFT;
    const int lim = min(SCNODES, N - v0);
    if (lim <= 0) return;
    int4* dst4 = reinterpret_cast<int4*>(&csr_src[(size_t)v0 * CAP]);
    const int4* src4 = reinterpret_cast<const int4*>(csrL);
    for (int i = t; i < lim * (CAP / 4); i += 1024) dst4[i] = src4[i];
    for (int i = t; i < lim; i += 1024) {
        int cv = cntL[i];
        cnt[v0 + i] = cv;
        dinv[v0 + i] = rsqrtf((float)cv + 1.0f);
    }
}

// ---------------- gemm2: hw2[N,64] = h[N,64](bf16) @ W2[64,47] (zero-padded), MFMA ------------

__global__ __launch_bounds__(256) void gemm2_mfma(const u16* __restrict__ X,
                                                  const float* __restrict__ W,
                                                  u16* __restrict__ OUT, int N) {
    __shared__ __align__(16) u16 W2t[64 * 72];   // [64 cols][72 k] bf16, 9216 B
    const int t = threadIdx.x;
    for (int i = t; i < 64 * 64; i += 256) {
        int k = i >> 6, c = i & 63;
        W2t[c * 72 + k] = (c < 47) ? f2bf(W[k * 47 + c]) : (u16)0;
    }
    __syncthreads();

    const int wave = t >> 6;
    const int lane = t & 63;
    const int rA = lane & 15;
    const int g  = lane >> 4;
    const int row0 = blockIdx.x * 64;
    const int m = row0 + wave * 16 + rA;
    f32x4 acc[4] = {{0.f,0.f,0.f,0.f},{0.f,0.f,0.f,0.f},
                    {0.f,0.f,0.f,0.f},{0.f,0.f,0.f,0.f}};

    #pragma unroll
    for (int s = 0; s < 2; s++) {
        bf16x8 a = {0,0,0,0,0,0,0,0};
        if (m < N) a = *reinterpret_cast<const bf16x8*>(&X[(size_t)m * 64 + s * 32 + g * 8]);
        #pragma unroll
        for (int ct = 0; ct < 4; ct++) {
            bf16x8 bfr = *reinterpret_cast<const bf16x8*>(
                &W2t[(ct * 16 + rA) * 72 + s * 32 + g * 8]);
            acc[ct] = __builtin_amdgcn_mfma_f32_16x16x32_bf16(a, bfr, acc[ct], 0, 0, 0);
        }
    }
    #pragma unroll
    for (int ct = 0; ct < 4; ct++)
        #pragma unroll
        for (int j = 0; j < 4; j++) {
            int mr = row0 + wave * 16 + g * 4 + j;
            if (mr < N) OUT[(size_t)mr * 64 + ct * 16 + rA] = f2bf(acc[ct][j]);
        }
}

// 8 bf16 (uint4) * w accumulated into acc[8]
__device__ __forceinline__ void fma_bf8(uint4 q, float w, float* acc) {
    acc[0] = fmaf(__uint_as_float(q.x << 16),          w, acc[0]);
    acc[1] = fmaf(__uint_as_float(q.x & 0xffff0000u),  w, acc[1]);
    acc[2] = fmaf(__uint_as_float(q.y << 16),          w, acc[2]);
    acc[3] = fmaf(__uint_as_float(q.y & 0xffff0000u),  w, acc[3]);
    acc[4] = fmaf(__uint_as_float(q.z << 16),          w, acc[4]);
    acc[5] = fmaf(__uint_as_float(q.z & 0xffff0000u),  w, acc[5]);
    acc[6] = fmaf(__uint_as_float(q.w << 16),          w, acc[6]);
    acc[7] = fmaf(__uint_as_float(q.w & 0xffff0000u),  w, acc[7]);
}

// Gather-accumulate over one 32-slot block. Row gathers are inline-asm volatile
// global_load_dwordx4 (un-collapsible -> all stay in flight until one vmcnt).
#define AGG_BLOCK(TBL, SRCV, SHIFT, UMAX)                                             \
    {                                                                                 \
        int s8[UMAX];                                                                 \
        _Pragma("unroll")                                                             \
        for (int u = 0; u < UMAX; u++)                                                \
            s8[u] = __shfl(SRCV, base + u * 4 + r);                                   \
        float d8[UMAX]; uint4 q8[UMAX];                                               \
        _Pragma("unroll")                                                             \
        for (int u = 0; u < UMAX; u++) {                                              \
            if ((SHIFT) + u * 4 < cemax) {                                            \
                d8[u] = dinv[s8[u]];                                                  \
                const u16* ap = &TBL[(size_t)s8[u] * 64 + b * 8];                     \
                asm volatile("global_load_dwordx4 %0, %1, off"                        \
                             : "=v"(q8[u]) : "v"(ap));                                \
            }                                                                         \
        }                                                                             \
        asm volatile("s_waitcnt vmcnt(0)" ::: "memory");                              \
        __builtin_amdgcn_sched_barrier(0);                                            \
        _Pragma("unroll")                                                             \
        for (int u = 0; u < UMAX; u++) {                                              \
            if ((SHIFT) + u * 4 < cemax) {                                            \
                int e = (SHIFT) + u * 4 + r;                                          \
                float w = (e <= c) ? d8[u] * dv : 0.f;                                \
                fma_bf8(q8[u], w, acc);                                               \
            }                                                                         \
        }                                                                             \
    }

// ---------------- layer-1 aggregation: h = relu(agg + xw/deg + b1), F=64, bf16 out -------------

__global__ __launch_bounds__(256, 4) void agg1_relu(const u16* __restrict__ xw,
                                                    const int* __restrict__ csr_src,
                                                    const int* __restrict__ cnt,
                                                    const float* __restrict__ dinv,
                                                    const float* __restrict__ bias,
                                                    u16* __restrict__ h, int N) {
    const int wid = (blockIdx.x * 256 + threadIdx.x) >> 6;
    const int lane = threadIdx.x & 63;
    const int v = wid * 2 + (lane >> 5);
    if (wid * 2 >= N) return;
    const bool okv = v < N;
    const int vs = okv ? v : 0;
    const int hl = lane & 31;
    int c = okv ? cnt[vs] : 0; if (c > CAP - 1) c = CAP - 1;
    const float dv = okv ? dinv[vs] : 0.f;
    int rawA = csr_src[vs * CAP + hl];
    int sA = (hl < c) ? rawA : ((hl == c) ? vs : 0);

    int ce = c + 1;
    int cemax = max(ce, __shfl_xor(ce, 32));
    const int r = hl >> 3, b = hl & 7;
    const int base = lane & 32;
    float acc[8] = {};

    AGG_BLOCK(xw, sA, 0, 8)
    if (cemax > 32) {   // rare (deg >= 32): slots 32..47
        int rawB = csr_src[vs * CAP + 32 + hl];   // hl>=16 reads pad, never selected
        int hl32 = hl + 32;
        int sB = (hl32 < c) ? rawB : ((hl32 == c) ? vs : 0);
        AGG_BLOCK(xw, sB, 32, 4)
    }

    #pragma unroll
    for (int u = 0; u < 8; u++) {
        acc[u] += __shfl_xor(acc[u], 8);
        acc[u] += __shfl_xor(acc[u], 16);
    }
    if (r == 0 && okv) {
        ushort4 oA, oB;
        oA.x = f2bf(fmaxf(acc[0] + bias[b * 8 + 0], 0.f));
        oA.y = f2bf(fmaxf(acc[1] + bias[b * 8 + 1], 0.f));
        oA.z = f2bf(fmaxf(acc[2] + bias[b * 8 + 2], 0.f));
        oA.w = f2bf(fmaxf(acc[3] + bias[b * 8 + 3], 0.f));
        oB.x = f2bf(fmaxf(acc[4] + bias[b * 8 + 4], 0.f));
        oB.y = f2bf(fmaxf(acc[5] + bias[b * 8 + 5], 0.f));
        oB.z = f2bf(fmaxf(acc[6] + bias[b * 8 + 6], 0.f));
        oB.w = f2bf(fmaxf(acc[7] + bias[b * 8 + 7], 0.f));
        u16* dstp = &h[(size_t)v * 64 + b * 8];
        *reinterpret_cast<ushort4*>(dstp)     = oA;
        *reinterpret_cast<ushort4*>(dstp + 4) = oB;
    }
}

// ---------------- layer-2 aggregation fused with log_softmax, F=47 (rows padded to 64) ----------

__global__ __launch_bounds__(256, 4) void agg2_lsm(const u16* __restrict__ hw,
                                                   const int* __restrict__ csr_src,
                                                   const int* __restrict__ cnt,
                                                   const float* __restrict__ dinv,
                                                   const float* __restrict__ bias,
                                                   float* __restrict__ out, int N) {
    const int wid = (blockIdx.x * 256 + threadIdx.x) >> 6;
    const int lane = threadIdx.x & 63;
    const int v = wid * 2 + (lane >> 5);
    if (wid * 2 >= N) return;
    const bool okv = v < N;
    const int vs = okv ? v : 0;
    const int hl = lane & 31;
    int c = okv ? cnt[vs] : 0; if (c > CAP - 1) c = CAP - 1;
    const float dv = okv ? dinv[vs] : 0.f;
    int rawA = csr_src[vs * CAP + hl];
    int sA = (hl < c) ? rawA : ((hl == c) ? vs : 0);

    int ce = c + 1;
    int cemax = max(ce, __shfl_xor(ce, 32));
    const int r = hl >> 3, b = hl & 7;
    const int base = lane & 32;
    float acc[8] = {};

    AGG_BLOCK(hw, sA, 0, 8)
    if (cemax > 32) {
        int rawB = csr_src[vs * CAP + 32 + hl];
        int hl32 = hl + 32;
        int sB = (hl32 < c) ? rawB : ((hl32 == c) ? vs : 0);
        AGG_BLOCK(hw, sB, 32, 4)
    }

    #pragma unroll
    for (int u = 0; u < 8; u++) {
        acc[u] += __shfl_xor(acc[u], 8);
        acc[u] += __shfl_xor(acc[u], 16);
    }
    const int f0 = b * 8;
    float val[8];
    #pragma unroll
    for (int u = 0; u < 8; u++) {
        int f = f0 + u;
        val[u] = (f < 47) ? acc[u] + bias[f] : -INFINITY;
    }
    float m = val[0];
    #pragma unroll
    for (int u = 1; u < 8; u++) m = fmaxf(m, val[u]);
    m = fmaxf(m, __shfl_xor(m, 1));
    m = fmaxf(m, __shfl_xor(m, 2));
    m = fmaxf(m, __shfl_xor(m, 4));
    float s = 0.f;
    #pragma unroll
    for (int u = 0; u < 8; u++)
        s += (f0 + u < 47) ? __expf(val[u] - m) : 0.f;
    s += __shfl_xor(s, 1);
    s += __shfl_xor(s, 2);
    s += __shfl_xor(s, 4);
    float ls = m + __logf(s);
    if (r == 0 && okv) {
        #pragma unroll
        for (int u = 0; u < 8; u++) {
            int f = f0 + u;
            if (f < 47) out[(size_t)v * 47 + f] = val[u] - ls;
        }
    }
}

// ---------------- launch ----------------

extern "C" void kernel_launch(void* const* d_in, const int* in_sizes, int n_in,
                              void* d_out, int out_size, void* d_ws, size_t ws_size,
                              hipStream_t stream) {
    const float* x  = (const float*)d_in[0];
    const int*   ei = (const int*)d_in[1];
    const float* W1 = (const float*)d_in[2];
    const float* b1 = (const float*)d_in[3];
    const float* W2 = (const float*)d_in[4];
    const float* b2 = (const float*)d_in[5];
    float* out = (float*)d_out;

    const int N = in_sizes[0] / 128;
    const int E = in_sizes[1] / 2;
    const int* src = ei;
    const int* dst = ei + E;
    const int NB = ((N - 1) >> NBSHIFT) + 1;   // 391 for N=100000

    char* ws = (char*)d_ws;
    size_t off = 0;
    auto alloc = [&](size_t bytes) {
        void* p = ws + off;
        off += (bytes + 255) & ~(size_t)255;
        return p;
    };
    int*   cnt      = (int*)  alloc((size_t)N * 4);
    int*   gtail    = (int*)  alloc((size_t)512 * 4);
    float* dinv     = (float*)alloc((size_t)N * 4);
    int*   csr_src  = (int*)  alloc(((size_t)N * CAP + 64) * 4);   // +pad for rawB overread
    u16*   xw1      = (u16*)  alloc((size_t)N * 64 * 2);
    int*   bucketed = (int*)  alloc((size_t)NB * BCAP * 4);        // 9.6 MB packed
    u16*   hbuf     = (u16*)  alloc((size_t)N * 64 * 2);
    u16*   hw2      = (u16*)  alloc((size_t)N * 64 * 2);

    hipMemsetAsync(gtail, 0, 512 * 4, stream);

    const int GB = (N + 63) / 64;              // 1563 gemm blocks (64 rows each)
    const int BINB = 512;
    const int seg = (E + BINB - 1) / BINB;     // 3125 <= EPT*256
    gemm1_bin<<<BINB + GB, 256, 0, stream>>>(x, W1, xw1, src, dst, gtail, bucketed,
                                             N, E, NB, seg, BINB);
    scatter_csr<<<NB, 1024, 0, stream>>>(bucketed, gtail, cnt, csr_src, dinv, N);
    agg1_relu<<<(N + 7) / 8, 256, 0, stream>>>(xw1, csr_src, cnt, dinv, b1, hbuf, N);
    gemm2_mfma<<<(N + 63) / 64, 256, 0, stream>>>(hbuf, W2, hw2, N);
    agg2_lsm<<<(N + 7) / 8, 256, 0, stream>>>(hw2, csr_src, cnt, dinv, b2, out, N);
}